// Round 14
// baseline (126.357 us; speedup 1.0000x reference)
//
#include <hip/hip_runtime.h>

// FANS: B=131072 rows x 16 states, MLP 12->64->64->1 with tanh, fp32 in/out.
// R31: inline-asm MFMA with VGPR accumulators. Four register-targeting
// rounds (R19 spill / R22 flat / R24 defeated / R29 flat) all failed the
// same way: intrinsic MFMAs ALWAYS put C/D in AGPRs; AGPRs are invisible to
// VGPR_Count (36-48 reported vs >=48 accum regs that must exist) and
// unsteerable by launch_bounds -> every occupancy experiment was turning a
// non-binding knob; unified ~100+ silently pins 4 waves/SIMD.
// Change: v_mfma_f32_32x32x16_f16 via asm with "+v" accumulator (gfx950
// unified file allows C/D in v[], ISA sec.10): AGPR use -> 0, VGPR_Count
// becomes truthful, shuttle (if any) dies. Hazards now ours: s_nop 1 before
// each MFMA (VALU-write->MFMA-read ~2cy); 3x s_nop 7 after chain-final
// MFMAs (MFMA-D->VALU-read, 16-pass); D-as-C chaining needs none (standard
// hand-asm GEMM). ~116 cy/tile overhead (~12%) buys decisive information.
// Base: R23 body (equal-best 64.8-66us), prefetch dropped (neutral, -12 regs).
// Predict: VGPR_Count -> 95-120 (decisive). If <=102: occ ~60%, dur 56-60.
// If >102: occ ~50%, dur 64-70 -> 4-wave cap is ALGORITHMIC -> with 11 flat
// rounds, that is the floor evidence. Tripwires: FETCH>>10MB -> spill,
// revert; absmax != 0.0009765625 -> hazard bug, revert.
// Kept: sequential c1-half lifetimes + sched_barrier pins, asm-VOP3P tanh,
// permlane32_swap H-exchange, weights in LDS frag layout, opaque-zero
// anti-LICM, CHUNK=4, split fdot2, launch_bounds(256,4).

#define N_STATES 16
#define CHUNK    4

typedef _Float16 f16x8  __attribute__((ext_vector_type(8)));
typedef float    f32x16 __attribute__((ext_vector_type(16)));
typedef __fp16   h2     __attribute__((ext_vector_type(2)));
typedef unsigned int u32x2 __attribute__((ext_vector_type(2)));

__device__ __forceinline__ h2 pack2(float a, float b) {
    return __builtin_amdgcn_cvt_pkrtz(a, b);
}
__device__ __forceinline__ unsigned int h2_bits(h2 v) {
    union { h2 h; unsigned int u; } x; x.h = v; return x.u;
}
__device__ __forceinline__ h2 bits_h2(unsigned int v) {
    union { unsigned int u; h2 h; } x; x.u = v; return x.h;
}
__device__ __forceinline__ f16x8 u4_to_h8(uint4 v) {
    union { uint4 u; f16x8 h; } x; x.u = v; return x.h;
}
__device__ __forceinline__ uint4 pk8(float4 a, float4 b) {
    return make_uint4(h2_bits(pack2(a.x, a.y)), h2_bits(pack2(a.z, a.w)),
                      h2_bits(pack2(b.x, b.y)), h2_bits(pack2(b.z, b.w)));
}

// MFMA in arch VGPRs ("+v" accumulator: read as C, written as D, same tuple
// -> in-place accumulate, no AGPRs). Leading s_nop 1 covers VALU->MFMA-read.
__device__ __forceinline__ void mfma_acc(f32x16& c, f16x8 a, f16x8 b) {
    asm("s_nop 1\n\t"
        "v_mfma_f32_32x32x16_f16 %0, %1, %2, %0"
        : "+v"(c) : "v"(a), "v"(b));
}
// Chain-final variant: trailing nops cover MFMA-D -> VALU-read (16-pass).
__device__ __forceinline__ void mfma_acc_fin(f32x16& c, f16x8 a, f16x8 b) {
    asm("s_nop 1\n\t"
        "v_mfma_f32_32x32x16_f16 %0, %1, %2, %0\n\t"
        "s_nop 7\n\t"
        "s_nop 7\n\t"
        "s_nop 7"
        : "+v"(c) : "v"(a), "v"(b));
}

// Packed-f16 tanh: clamp(+-1.25) then odd Chebyshev poly, VOP3P asm.
__device__ __forceinline__ h2 tanh_pk(h2 x) {
    const h2 hi = {(__fp16)1.25f, (__fp16)1.25f};
    const h2 lo = {(__fp16)-1.25f, (__fp16)-1.25f};
    const h2 k4 = {(__fp16)0.00598591f, (__fp16)0.00598591f};
    const h2 k3 = {(__fp16)-0.03807894f, (__fp16)-0.03807894f};
    const h2 k2 = {(__fp16)0.12576901f, (__fp16)0.12576901f};
    const h2 k1 = {(__fp16)-0.33203310f, (__fp16)-0.33203310f};
    const h2 k0 = {(__fp16)0.99998110f, (__fp16)0.99998110f};
    h2 s, p;
    asm("v_pk_max_f16 %0, %0, %3\n\t"      // x = max(x, lo)
        "v_pk_min_f16 %0, %0, %4\n\t"      // x = min(x, hi)
        "v_pk_mul_f16 %1, %0, %0\n\t"      // s = x*x
        "v_pk_fma_f16 %2, %1, %5, %6\n\t"  // p = s*k4 + k3
        "v_pk_fma_f16 %2, %1, %2, %7\n\t"  // p = s*p + k2
        "v_pk_fma_f16 %2, %1, %2, %8\n\t"  // p = s*p + k1
        "v_pk_fma_f16 %2, %1, %2, %9\n\t"  // p = s*p + k0
        "v_pk_mul_f16 %0, %0, %2"          // x = x*p
        : "+v"(x), "=&v"(s), "=&v"(p)
        : "v"(lo), "v"(hi), "v"(k4), "v"(k3), "v"(k2), "v"(k1), "v"(k0));
    return x;
}

__global__ __launch_bounds__(256, 4) void fans_mfma_kernel(
    const float* __restrict__ x_f, const float* __restrict__ x_b,
    const float* __restrict__ u,   const float* __restrict__ W0,
    const float* __restrict__ W1,  const float* __restrict__ W2,
    float* __restrict__ out)
{
    __shared__ __align__(16) uint4 zplA[256];              // 4 KB: z dwords 0..3
    __shared__ __align__(16) uint2 zplB[256];              // 2 KB: u pair
    __shared__ __align__(16) uint4 sA1[8][64];             // 8 KB: W1 frags [Mh*4+kc][h*32+n]
    __shared__ __align__(16) uint4 sA0[2][64];             // 2 KB: W0 frags [Mh][h*32+n]
    __shared__ __align__(16) unsigned int w2l[32];         // 128 B: W2 pair-packed

    const int s   = blockIdx.y;
    const int tid = threadIdx.x;
    const int b0  = blockIdx.x * (256 * CHUNK);

    const int lid = tid & 63;
    const int w   = tid >> 6;     // wave id; wave w owns local rows [64w,64w+64)
    const int n   = lid & 31;     // batch row within 32-tile / feat row for A
    const int h   = lid >> 5;     // K-half (k = 8h+j)

    // ---- stage weights to LDS in frag layout (once per block) ----
    // sA1[Mh*4+kc][h*32+n] = W1[s][32Mh+n][16kc+8h+0..7] as 8 x f16
    {
        const int r  = tid >> 2;          // 0..63 feature row
        const int kc = tid & 3;           // 0..3 K-chunk
        const float* p = W1 + s * 4096 + r * 64 + kc * 16;
        const float4 v0 = ((const float4*)p)[0];
        const float4 v1 = ((const float4*)p)[1];
        const float4 v2 = ((const float4*)p)[2];
        const float4 v3 = ((const float4*)p)[3];
        sA1[(r >> 5) * 4 + kc][(r & 31)]      = pk8(v0, v1);  // h=0: cols +0..7
        sA1[(r >> 5) * 4 + kc][32 + (r & 31)] = pk8(v2, v3);  // h=1: cols +8..15
    }
    // sA0[Mh][h*32+n] = W0[s][32Mh+n][8h+0..7] (h=1: cols 8..11 + zero pad)
    if (tid < 128) {
        const int r  = tid >> 1;          // 0..63 feature row
        const int hh = tid & 1;
        const float* base = W0 + s * 768 + r * 12;
        uint4 v;
        if (hh == 0) {
            const float4 v0 = *(const float4*)(base + 0);
            const float4 v1 = *(const float4*)(base + 4);
            v = pk8(v0, v1);
        } else {
            const float4 v0 = *(const float4*)(base + 8);   // k=8..11
            v = make_uint4(h2_bits(pack2(v0.x, v0.y)), h2_bits(pack2(v0.z, v0.w)), 0u, 0u);
        }
        sA0[r >> 5][hh * 32 + (r & 31)] = v;
    }
    // w2l[i] = pack2(W2[s][2i], W2[s][2i+1]); layer-3 reads broadcast per h.
    if (tid < 32) {
        const float* w2s = W2 + s * 64;
        w2l[tid] = h2_bits(pack2(w2s[2 * tid], w2s[2 * tid + 1]));
    }
    __syncthreads();

    const int wrap = (s > 8) ? (s - 8) : 0;   // IDX[s] = {0..wrap-1}++{s..15}

    #pragma unroll 1
    for (int ch = 0; ch < CHUNK; ++ch) {
        const int rbase = b0 + ch * 256;

        // ---- phase 1: gather z for own row, pack, write planes ----
        {
            const int row = rbase + tid;
            float zs[8];
            #pragma unroll
            for (int j = 0; j < 8; ++j) {
                const int idx = (j < wrap) ? j : (s + j - wrap);  // uniform
                zs[j] = (idx < 8) ? x_f[row * 8 + idx] : x_b[row * 8 + (idx - 8)];
            }
            const float4 uv = *(const float4*)(u + row * 4);
            zplA[tid] = make_uint4(h2_bits(pack2(zs[0], zs[1])), h2_bits(pack2(zs[2], zs[3])),
                                   h2_bits(pack2(zs[4], zs[5])), h2_bits(pack2(zs[6], zs[7])));
            zplB[tid] = make_uint2(h2_bits(pack2(uv.x, uv.y)), h2_bits(pack2(uv.z, uv.w)));
        }
        // No barrier: wave w reads only rows [64w,64w+64) it wrote itself;
        // weight LDS is read-only after the initial sync.

        // ---- phase 2: two 32-row tiles ----
        #pragma unroll
        for (int m = 0; m < 2; ++m) {
            const int rowb = 64 * w + 32 * m;

            // Opaque zero: defeats LICM/CSE so weight ds_reads stay per-tile.
            unsigned int zero = 0;
            asm("" : "+v"(zero));
            const int lz = lid + (int)zero;

            // z B-frag: B[k=8h+j][n]: h=0 -> z dwords 0..3; h=1 -> u pair + 0
            f16x8 zf;
            if (h == 0) {
                zf = u4_to_h8(zplA[rowb + n]);
            } else {
                const uint2 b = zplB[rowb + n];
                zf = u4_to_h8(make_uint4(b.x, b.y, 0u, 0u));
            }

            const f32x16 z16 = {0.f,0.f,0.f,0.f,0.f,0.f,0.f,0.f,
                                0.f,0.f,0.f,0.f,0.f,0.f,0.f,0.f};
            f32x16 c2a = z16, c2b = z16;

            // ---- per half: c1 -> tanh -> 2 kc MFMAs; c1 regs reused across
            // halves (sched_barrier pins the lifetime). All accums in VGPRs.
            #pragma unroll
            for (int half = 0; half < 2; ++half) {
                const f16x8 a0f = u4_to_h8(sA0[half][lz]);
                f32x16 c1 = z16;
                mfma_acc_fin(c1, a0f, zf);          // fin: tanh reads D next
                unsigned int t[8];
                #pragma unroll
                for (int a = 0; a < 4; ++a) {
                    t[2 * a + 0] = h2_bits(tanh_pk(pack2(c1[4 * a],     c1[4 * a + 1])));
                    t[2 * a + 1] = h2_bits(tanh_pk(pack2(c1[4 * a + 2], c1[4 * a + 3])));
                }
                __builtin_amdgcn_sched_barrier(0);
                #pragma unroll
                for (int kk = 0; kk < 2; ++kk) {
                    const int kc = 2 * half + kk;         // 0..3
                    const int q  = 4 * kk;
                    u32x2 r0 = __builtin_amdgcn_permlane32_swap(t[q + 0], t[q + 2], false, false);
                    u32x2 r1 = __builtin_amdgcn_permlane32_swap(t[q + 1], t[q + 3], false, false);
                    const f16x8 hb  = u4_to_h8(make_uint4(r0.x, r1.x, r0.y, r1.y));
                    const f16x8 w1a = u4_to_h8(sA1[kc][lz]);
                    const f16x8 w1b = u4_to_h8(sA1[4 + kc][lz]);
                    if (half == 1 && kk == 1) {
                        mfma_acc_fin(c2a, w1a, hb);   // layer-3 reads D next
                        mfma_acc_fin(c2b, w1b, hb);
                    } else {
                        mfma_acc(c2a, w1a, hb);
                        mfma_acc(c2b, w1b, hb);
                    }
                }
                __builtin_amdgcn_sched_barrier(0);
            }

            // layer 3: packed tanh + v_dot2; W2 pairs broadcast-read from LDS.
            // Split accumulators: 2-deep chains instead of 4-deep.
            const unsigned int* w2z = &w2l[zero];
            float p0 = 0.f, p1 = 0.f, q0 = 0.f, q1 = 0.f;
            #pragma unroll
            for (int a = 0; a < 4; ++a) {
                const int r = 4 * a;
                const uint2 wa = *(const uint2*)&w2z[4 * a + 2 * h];        // Mh=0
                const uint2 wb = *(const uint2*)&w2z[16 + 4 * a + 2 * h];   // Mh=1
                if (a & 1) {
                    p1 = __builtin_amdgcn_fdot2(tanh_pk(pack2(c2a[r], c2a[r + 1])), bits_h2(wa.x), p1, false);
                    p1 = __builtin_amdgcn_fdot2(tanh_pk(pack2(c2a[r + 2], c2a[r + 3])), bits_h2(wa.y), p1, false);
                    q1 = __builtin_amdgcn_fdot2(tanh_pk(pack2(c2b[r], c2b[r + 1])), bits_h2(wb.x), q1, false);
                    q1 = __builtin_amdgcn_fdot2(tanh_pk(pack2(c2b[r + 2], c2b[r + 3])), bits_h2(wb.y), q1, false);
                } else {
                    p0 = __builtin_amdgcn_fdot2(tanh_pk(pack2(c2a[r], c2a[r + 1])), bits_h2(wa.x), p0, false);
                    p0 = __builtin_amdgcn_fdot2(tanh_pk(pack2(c2a[r + 2], c2a[r + 3])), bits_h2(wa.y), p0, false);
                    q0 = __builtin_amdgcn_fdot2(tanh_pk(pack2(c2b[r], c2b[r + 1])), bits_h2(wb.x), q0, false);
                    q0 = __builtin_amdgcn_fdot2(tanh_pk(pack2(c2b[r + 2], c2b[r + 3])), bits_h2(wb.y), q0, false);
                }
            }
            float acc = (p0 + p1) + (q0 + q1);
            acc += __shfl_xor(acc, 32);       // combine h=0/h=1 halves

            if (lid < 32)
                out[(rbase + rowb + n) * N_STATES + s] = acc;
        }
    }
}

extern "C" void kernel_launch(void* const* d_in, const int* in_sizes, int n_in,
                              void* d_out, int out_size, void* d_ws, size_t ws_size,
                              hipStream_t stream) {
    const float* x_f = (const float*)d_in[0];
    const float* x_b = (const float*)d_in[1];
    const float* u   = (const float*)d_in[2];
    const float* W0  = (const float*)d_in[3];
    const float* W1  = (const float*)d_in[4];
    const float* W2  = (const float*)d_in[5];
    float* out = (float*)d_out;

    const int nb = in_sizes[0] / 8;                 // 131072 = 128 * 1024
    dim3 grid(nb / (256 * CHUNK), N_STATES);        // (128, 16) = 2048 blocks
    fans_mfma_kernel<<<grid, 256, 0, stream>>>(x_f, x_b, u, W0, W1, W2, out);
}

// Round 15
// 124.833 us; speedup vs baseline: 1.0122x; 1.0122x over previous
//
#include <hip/hip_runtime.h>

// FANS: B=131072 rows x 16 states, MLP 12->64->64->1 with tanh, fp32 in/out.
// R32: intra-wave ILP - two states per block. Framing after 11 flat rounds:
// MfmaUtil 13% (=20.5k/158k cyc exact), real per-SIMD VALU ~23% (VALUBusy
// ~62% is the 4-SIMD union), HBM 8%, LDS ~27% -> NOTHING saturated; latency-
// bound at 4 waves/SIMD running ONE serial chain each. 5 occupancy attacks
// prove >4 waves unreachable (unified file ~100+, AGPR-resident accums).
// Untested lever: more INDEPENDENT chains per wave.
// Change: block = state pair (s0,s1); per chunk each wave runs 4 mutually
// independent tiles (2 states x 2 m), adjacent in program order, NO sched
// pins -> scheduler overlaps tile i's MFMA-chain latency with tile i+1's
// layer1/tanh. CHUNK=2 keeps grid 2048 + same total staging as R20.
// LDS 32.3KB -> 4 blocks/CU (same 4 waves/SIMD; isolates ILP).
// R31's asm-MFMA reverted (cost 5us: nops + AGPR shuttle of "+v" accums).
// Predict: dur 66->50-56us if ILP binds; VALUBusy 62->75-85; FETCH ~6.5MB
// (>>10MB -> over-pipelined spill -> pin st-tiles apart); absmax identical.
// Falsifier: flat -> all lever classes measured flat -> declare latency
// floor. Kept: intrinsic MFMA, asm-VOP3P tanh, permlane32 H-exchange,
// weights in LDS frag layout, opaque-zero anti-LICM, split fdot2, (256,4).

#define N_STATES 16
#define CHUNK    2

typedef _Float16 f16x8  __attribute__((ext_vector_type(8)));
typedef float    f32x16 __attribute__((ext_vector_type(16)));
typedef __fp16   h2     __attribute__((ext_vector_type(2)));
typedef unsigned int u32x2 __attribute__((ext_vector_type(2)));

__device__ __forceinline__ h2 pack2(float a, float b) {
    return __builtin_amdgcn_cvt_pkrtz(a, b);
}
__device__ __forceinline__ unsigned int h2_bits(h2 v) {
    union { h2 h; unsigned int u; } x; x.h = v; return x.u;
}
__device__ __forceinline__ h2 bits_h2(unsigned int v) {
    union { unsigned int u; h2 h; } x; x.u = v; return x.h;
}
__device__ __forceinline__ f16x8 u4_to_h8(uint4 v) {
    union { uint4 u; f16x8 h; } x; x.u = v; return x.h;
}
__device__ __forceinline__ uint4 pk8(float4 a, float4 b) {
    return make_uint4(h2_bits(pack2(a.x, a.y)), h2_bits(pack2(a.z, a.w)),
                      h2_bits(pack2(b.x, b.y)), h2_bits(pack2(b.z, b.w)));
}

// Packed-f16 tanh: clamp(+-1.25) then odd Chebyshev poly, VOP3P asm.
__device__ __forceinline__ h2 tanh_pk(h2 x) {
    const h2 hi = {(__fp16)1.25f, (__fp16)1.25f};
    const h2 lo = {(__fp16)-1.25f, (__fp16)-1.25f};
    const h2 k4 = {(__fp16)0.00598591f, (__fp16)0.00598591f};
    const h2 k3 = {(__fp16)-0.03807894f, (__fp16)-0.03807894f};
    const h2 k2 = {(__fp16)0.12576901f, (__fp16)0.12576901f};
    const h2 k1 = {(__fp16)-0.33203310f, (__fp16)-0.33203310f};
    const h2 k0 = {(__fp16)0.99998110f, (__fp16)0.99998110f};
    h2 s, p;
    asm("v_pk_max_f16 %0, %0, %3\n\t"
        "v_pk_min_f16 %0, %0, %4\n\t"
        "v_pk_mul_f16 %1, %0, %0\n\t"
        "v_pk_fma_f16 %2, %1, %5, %6\n\t"
        "v_pk_fma_f16 %2, %1, %2, %7\n\t"
        "v_pk_fma_f16 %2, %1, %2, %8\n\t"
        "v_pk_fma_f16 %2, %1, %2, %9\n\t"
        "v_pk_mul_f16 %0, %0, %2"
        : "+v"(x), "=&v"(s), "=&v"(p)
        : "v"(lo), "v"(hi), "v"(k4), "v"(k3), "v"(k2), "v"(k1), "v"(k0));
    return x;
}

__global__ __launch_bounds__(256, 4) void fans_mfma_kernel(
    const float* __restrict__ x_f, const float* __restrict__ x_b,
    const float* __restrict__ u,   const float* __restrict__ W0,
    const float* __restrict__ W1,  const float* __restrict__ W2,
    float* __restrict__ out)
{
    __shared__ __align__(16) uint4 zplA[2][256];            // 8 KB
    __shared__ __align__(16) uint2 zplB[2][256];            // 4 KB
    __shared__ __align__(16) uint4 sA1[2][8][64];           // 16 KB
    __shared__ __align__(16) uint4 sA0[2][2][64];           // 4 KB
    __shared__ __align__(16) unsigned int w2l[2][32];       // 256 B

    const int sp  = blockIdx.y;            // state pair 0..7 -> s = 2sp+st
    const int tid = threadIdx.x;
    const int b0  = blockIdx.x * (256 * CHUNK);

    const int lid = tid & 63;
    const int w   = tid >> 6;
    const int n   = lid & 31;
    const int h   = lid >> 5;

    // ---- stage weights for BOTH states (frag layout, once per block) ----
    #pragma unroll
    for (int st = 0; st < 2; ++st) {
        const int s = 2 * sp + st;
        {
            const int r  = tid >> 2;
            const int kc = tid & 3;
            const float* p = W1 + s * 4096 + r * 64 + kc * 16;
            const float4 v0 = ((const float4*)p)[0];
            const float4 v1 = ((const float4*)p)[1];
            const float4 v2 = ((const float4*)p)[2];
            const float4 v3 = ((const float4*)p)[3];
            sA1[st][(r >> 5) * 4 + kc][(r & 31)]      = pk8(v0, v1);
            sA1[st][(r >> 5) * 4 + kc][32 + (r & 31)] = pk8(v2, v3);
        }
        if (tid < 128) {
            const int r  = tid >> 1;
            const int hh = tid & 1;
            const float* base = W0 + s * 768 + r * 12;
            uint4 v;
            if (hh == 0) {
                const float4 v0 = *(const float4*)(base + 0);
                const float4 v1 = *(const float4*)(base + 4);
                v = pk8(v0, v1);
            } else {
                const float4 v0 = *(const float4*)(base + 8);
                v = make_uint4(h2_bits(pack2(v0.x, v0.y)), h2_bits(pack2(v0.z, v0.w)), 0u, 0u);
            }
            sA0[st][r >> 5][hh * 32 + (r & 31)] = v;
        }
        if (tid < 32) {
            const float* w2s = W2 + s * 64;
            w2l[st][tid] = h2_bits(pack2(w2s[2 * tid], w2s[2 * tid + 1]));
        }
    }
    __syncthreads();

    #pragma unroll 1
    for (int ch = 0; ch < CHUNK; ++ch) {
        const int rbase = b0 + ch * 256;

        // ---- phase 1: gather z for own row, both states ----
        #pragma unroll
        for (int st = 0; st < 2; ++st) {
            const int s    = 2 * sp + st;
            const int wrap = (s > 8) ? (s - 8) : 0;   // IDX[s] = {0..wrap-1}++{s..15}
            const int row  = rbase + tid;
            float zs[8];
            #pragma unroll
            for (int j = 0; j < 8; ++j) {
                const int idx = (j < wrap) ? j : (s + j - wrap);  // uniform
                zs[j] = (idx < 8) ? x_f[row * 8 + idx] : x_b[row * 8 + (idx - 8)];
            }
            const float4 uvv = *(const float4*)(u + row * 4);
            zplA[st][tid] = make_uint4(h2_bits(pack2(zs[0], zs[1])), h2_bits(pack2(zs[2], zs[3])),
                                       h2_bits(pack2(zs[4], zs[5])), h2_bits(pack2(zs[6], zs[7])));
            zplB[st][tid] = make_uint2(h2_bits(pack2(uvv.x, uvv.y)), h2_bits(pack2(uvv.z, uvv.w)));
        }
        // No barrier: wave w reads only rows [64w,64w+64) it wrote itself.

        // ---- phase 2: 4 independent tiles (2 m x 2 states), no pins ----
        #pragma unroll
        for (int m = 0; m < 2; ++m) {
            const int rowb = 64 * w + 32 * m;
            #pragma unroll
            for (int st = 0; st < 2; ++st) {
                // Opaque zero: defeats LICM/CSE so weight ds_reads stay per-tile.
                unsigned int zero = 0;
                asm("" : "+v"(zero));
                const int lz = lid + (int)zero;

                f16x8 zf;
                if (h == 0) {
                    zf = u4_to_h8(zplA[st][rowb + n]);
                } else {
                    const uint2 b = zplB[st][rowb + n];
                    zf = u4_to_h8(make_uint4(b.x, b.y, 0u, 0u));
                }

                const f32x16 z16 = {0.f,0.f,0.f,0.f,0.f,0.f,0.f,0.f,
                                    0.f,0.f,0.f,0.f,0.f,0.f,0.f,0.f};
                f32x16 c2a = z16, c2b = z16;

                #pragma unroll
                for (int half = 0; half < 2; ++half) {
                    const f16x8 a0f = u4_to_h8(sA0[st][half][lz]);
                    f32x16 c1 = __builtin_amdgcn_mfma_f32_32x32x16_f16(a0f, zf, z16, 0, 0, 0);
                    unsigned int t[8];
                    #pragma unroll
                    for (int a = 0; a < 4; ++a) {
                        t[2 * a + 0] = h2_bits(tanh_pk(pack2(c1[4 * a],     c1[4 * a + 1])));
                        t[2 * a + 1] = h2_bits(tanh_pk(pack2(c1[4 * a + 2], c1[4 * a + 3])));
                    }
                    #pragma unroll
                    for (int kk = 0; kk < 2; ++kk) {
                        const int kc = 2 * half + kk;
                        const int q  = 4 * kk;
                        u32x2 r0 = __builtin_amdgcn_permlane32_swap(t[q + 0], t[q + 2], false, false);
                        u32x2 r1 = __builtin_amdgcn_permlane32_swap(t[q + 1], t[q + 3], false, false);
                        const f16x8 hb  = u4_to_h8(make_uint4(r0.x, r1.x, r0.y, r1.y));
                        const f16x8 w1a = u4_to_h8(sA1[st][kc][lz]);
                        const f16x8 w1b = u4_to_h8(sA1[st][4 + kc][lz]);
                        c2a = __builtin_amdgcn_mfma_f32_32x32x16_f16(w1a, hb, c2a, 0, 0, 0);
                        c2b = __builtin_amdgcn_mfma_f32_32x32x16_f16(w1b, hb, c2b, 0, 0, 0);
                    }
                }

                // layer 3: packed tanh + v_dot2; W2 broadcast from LDS.
                const unsigned int* w2z = &w2l[st][zero];
                float p0 = 0.f, p1 = 0.f, q0 = 0.f, q1 = 0.f;
                #pragma unroll
                for (int a = 0; a < 4; ++a) {
                    const int r = 4 * a;
                    const uint2 wa = *(const uint2*)&w2z[4 * a + 2 * h];
                    const uint2 wb = *(const uint2*)&w2z[16 + 4 * a + 2 * h];
                    if (a & 1) {
                        p1 = __builtin_amdgcn_fdot2(tanh_pk(pack2(c2a[r], c2a[r + 1])), bits_h2(wa.x), p1, false);
                        p1 = __builtin_amdgcn_fdot2(tanh_pk(pack2(c2a[r + 2], c2a[r + 3])), bits_h2(wa.y), p1, false);
                        q1 = __builtin_amdgcn_fdot2(tanh_pk(pack2(c2b[r], c2b[r + 1])), bits_h2(wb.x), q1, false);
                        q1 = __builtin_amdgcn_fdot2(tanh_pk(pack2(c2b[r + 2], c2b[r + 3])), bits_h2(wb.y), q1, false);
                    } else {
                        p0 = __builtin_amdgcn_fdot2(tanh_pk(pack2(c2a[r], c2a[r + 1])), bits_h2(wa.x), p0, false);
                        p0 = __builtin_amdgcn_fdot2(tanh_pk(pack2(c2a[r + 2], c2a[r + 3])), bits_h2(wa.y), p0, false);
                        q0 = __builtin_amdgcn_fdot2(tanh_pk(pack2(c2b[r], c2b[r + 1])), bits_h2(wb.x), q0, false);
                        q0 = __builtin_amdgcn_fdot2(tanh_pk(pack2(c2b[r + 2], c2b[r + 3])), bits_h2(wb.y), q0, false);
                    }
                }
                float acc = (p0 + p1) + (q0 + q1);
                acc += __shfl_xor(acc, 32);       // combine h=0/h=1 halves

                if (lid < 32)
                    out[(rbase + rowb + n) * N_STATES + 2 * sp + st] = acc;
            }
        }
    }
}

extern "C" void kernel_launch(void* const* d_in, const int* in_sizes, int n_in,
                              void* d_out, int out_size, void* d_ws, size_t ws_size,
                              hipStream_t stream) {
    const float* x_f = (const float*)d_in[0];
    const float* x_b = (const float*)d_in[1];
    const float* u   = (const float*)d_in[2];
    const float* W0  = (const float*)d_in[3];
    const float* W1  = (const float*)d_in[4];
    const float* W2  = (const float*)d_in[5];
    float* out = (float*)d_out;

    const int nb = in_sizes[0] / 8;                     // 131072 rows
    dim3 grid(nb / (256 * CHUNK), N_STATES / 2);        // (256, 8) = 2048 blocks
    fans_mfma_kernel<<<grid, 256, 0, stream>>>(x_f, x_b, u, W0, W1, W2, out);
}

// Round 16
// 121.767 us; speedup vs baseline: 1.0377x; 1.0252x over previous
//
#include <hip/hip_runtime.h>

// FANS: B=131072 rows x 16 states, MLP 12->64->64->1 with tanh, fp32 in/out.
// R33: the 64-reg / 8-wave attack. Reframe: occupancy is QUANTIZED at
// unified-reg boundaries 64/128/256 (m69: waves halve there; no 5/6-wave
// step). Our ~90-110 unified always lands in (64,128] -> exactly 4
// waves/SIMD, which is why 13 rounds of occupancy work never moved it:
// every target (85/95/102) was INSIDE the bucket. Only unified<=64 -> 8
// waves/SIMD (2x latency hiding) is reachable. LDS 16.9KB x 8 blk = 135KB
// fits; grid 2048 = 8 blk/CU exactly.
// Structure for minimal liveness:
//   zf -> c1=MFMA(a0[0]) -> t[0..7] -> [pin] -> c1=MFMA(a0[1]) -> t[8..15]
//   -> [pin] -> chainA: c2=4xMFMA(sA1[0..3], hb from t) + layer3A -> [pin]
//   -> chainB: c2=4xMFMA(sA1[4..7], hb recomputed) + layer3B
// One c1/c2 (16 AGPR, disjoint lifetimes share regs), t=16 arch, hb
// recomputed per chain (+8 permlanes/tile ~ noise). Peak unified ~56.
// Enforced by __launch_bounds__(256,8) (budget 64). Prefetch dropped
// (neutral, +12 regs).
// Predict: Occupancy 45 -> 85-100% (decisive), dispatch 66 -> 45-55us,
// VGPR 36-44, FETCH ~6.4MB. Tripwires: FETCH>>10MB -> budget infeasible,
// revert+concede; occ ~90 but dur flat -> latency theory falsified, concede
// floor. absmax must stay 0.0009765625.
// Kept: intrinsic MFMA, asm-VOP3P tanh, permlane32 H-exchange, weights in
// LDS frag layout, opaque-zero anti-LICM, CHUNK=4, split fdot2.

#define N_STATES 16
#define CHUNK    4

typedef _Float16 f16x8  __attribute__((ext_vector_type(8)));
typedef float    f32x16 __attribute__((ext_vector_type(16)));
typedef __fp16   h2     __attribute__((ext_vector_type(2)));
typedef unsigned int u32x2 __attribute__((ext_vector_type(2)));

__device__ __forceinline__ h2 pack2(float a, float b) {
    return __builtin_amdgcn_cvt_pkrtz(a, b);
}
__device__ __forceinline__ unsigned int h2_bits(h2 v) {
    union { h2 h; unsigned int u; } x; x.h = v; return x.u;
}
__device__ __forceinline__ h2 bits_h2(unsigned int v) {
    union { unsigned int u; h2 h; } x; x.u = v; return x.h;
}
__device__ __forceinline__ f16x8 u4_to_h8(uint4 v) {
    union { uint4 u; f16x8 h; } x; x.u = v; return x.h;
}
__device__ __forceinline__ uint4 pk8(float4 a, float4 b) {
    return make_uint4(h2_bits(pack2(a.x, a.y)), h2_bits(pack2(a.z, a.w)),
                      h2_bits(pack2(b.x, b.y)), h2_bits(pack2(b.z, b.w)));
}

// Packed-f16 tanh: clamp(+-1.25) then odd Chebyshev poly, VOP3P asm.
__device__ __forceinline__ h2 tanh_pk(h2 x) {
    const h2 hi = {(__fp16)1.25f, (__fp16)1.25f};
    const h2 lo = {(__fp16)-1.25f, (__fp16)-1.25f};
    const h2 k4 = {(__fp16)0.00598591f, (__fp16)0.00598591f};
    const h2 k3 = {(__fp16)-0.03807894f, (__fp16)-0.03807894f};
    const h2 k2 = {(__fp16)0.12576901f, (__fp16)0.12576901f};
    const h2 k1 = {(__fp16)-0.33203310f, (__fp16)-0.33203310f};
    const h2 k0 = {(__fp16)0.99998110f, (__fp16)0.99998110f};
    h2 s, p;
    asm("v_pk_max_f16 %0, %0, %3\n\t"
        "v_pk_min_f16 %0, %0, %4\n\t"
        "v_pk_mul_f16 %1, %0, %0\n\t"
        "v_pk_fma_f16 %2, %1, %5, %6\n\t"
        "v_pk_fma_f16 %2, %1, %2, %7\n\t"
        "v_pk_fma_f16 %2, %1, %2, %8\n\t"
        "v_pk_fma_f16 %2, %1, %2, %9\n\t"
        "v_pk_mul_f16 %0, %0, %2"
        : "+v"(x), "=&v"(s), "=&v"(p)
        : "v"(lo), "v"(hi), "v"(k4), "v"(k3), "v"(k2), "v"(k1), "v"(k0));
    return x;
}

__global__ __launch_bounds__(256, 8) void fans_mfma_kernel(
    const float* __restrict__ x_f, const float* __restrict__ x_b,
    const float* __restrict__ u,   const float* __restrict__ W0,
    const float* __restrict__ W1,  const float* __restrict__ W2,
    float* __restrict__ out)
{
    __shared__ __align__(16) uint4 zplA[256];              // 4 KB: z dwords 0..3
    __shared__ __align__(16) uint2 zplB[256];              // 2 KB: u pair
    __shared__ __align__(16) uint4 sA1[8][64];             // 8 KB: W1 frags
    __shared__ __align__(16) uint4 sA0[2][64];             // 2 KB: W0 frags
    __shared__ __align__(16) unsigned int w2l[32];         // 128 B: W2 pairs

    const int s   = blockIdx.y;
    const int tid = threadIdx.x;
    const int b0  = blockIdx.x * (256 * CHUNK);

    const int lid = tid & 63;
    const int w   = tid >> 6;     // wave id; wave w owns local rows [64w,64w+64)
    const int n   = lid & 31;     // batch row within 32-tile / feat row for A
    const int h   = lid >> 5;     // K-half (k = 8h+j)

    // ---- stage weights to LDS in frag layout (once per block) ----
    {
        const int r  = tid >> 2;          // 0..63 feature row
        const int kc = tid & 3;           // 0..3 K-chunk
        const float* p = W1 + s * 4096 + r * 64 + kc * 16;
        const float4 v0 = ((const float4*)p)[0];
        const float4 v1 = ((const float4*)p)[1];
        const float4 v2 = ((const float4*)p)[2];
        const float4 v3 = ((const float4*)p)[3];
        sA1[(r >> 5) * 4 + kc][(r & 31)]      = pk8(v0, v1);  // h=0 cols
        sA1[(r >> 5) * 4 + kc][32 + (r & 31)] = pk8(v2, v3);  // h=1 cols
    }
    if (tid < 128) {
        const int r  = tid >> 1;
        const int hh = tid & 1;
        const float* base = W0 + s * 768 + r * 12;
        uint4 v;
        if (hh == 0) {
            const float4 v0 = *(const float4*)(base + 0);
            const float4 v1 = *(const float4*)(base + 4);
            v = pk8(v0, v1);
        } else {
            const float4 v0 = *(const float4*)(base + 8);   // k=8..11
            v = make_uint4(h2_bits(pack2(v0.x, v0.y)), h2_bits(pack2(v0.z, v0.w)), 0u, 0u);
        }
        sA0[r >> 5][hh * 32 + (r & 31)] = v;
    }
    if (tid < 32) {
        const float* w2s = W2 + s * 64;
        w2l[tid] = h2_bits(pack2(w2s[2 * tid], w2s[2 * tid + 1]));
    }
    __syncthreads();

    const int wrap = (s > 8) ? (s - 8) : 0;   // IDX[s] = {0..wrap-1}++{s..15}

    #pragma unroll 1
    for (int ch = 0; ch < CHUNK; ++ch) {
        const int rbase = b0 + ch * 256;

        // ---- phase 1: gather z for own row, pack, write planes ----
        {
            const int row = rbase + tid;
            float zs[8];
            #pragma unroll
            for (int j = 0; j < 8; ++j) {
                const int idx = (j < wrap) ? j : (s + j - wrap);  // uniform
                zs[j] = (idx < 8) ? x_f[row * 8 + idx] : x_b[row * 8 + (idx - 8)];
            }
            const float4 uv = *(const float4*)(u + row * 4);
            zplA[tid] = make_uint4(h2_bits(pack2(zs[0], zs[1])), h2_bits(pack2(zs[2], zs[3])),
                                   h2_bits(pack2(zs[4], zs[5])), h2_bits(pack2(zs[6], zs[7])));
            zplB[tid] = make_uint2(h2_bits(pack2(uv.x, uv.y)), h2_bits(pack2(uv.z, uv.w)));
        }
        // No barrier: wave w reads only rows [64w,64w+64) it wrote itself.

        // ---- phase 2: two 32-row tiles ----
        #pragma unroll
        for (int m = 0; m < 2; ++m) {
            const int rowb = 64 * w + 32 * m;

            // Opaque zero: defeats LICM/CSE so weight ds_reads stay per-tile.
            unsigned int zero = 0;
            asm("" : "+v"(zero));
            const int lz = lid + (int)zero;

            // z B-frag: h=0 -> z dwords 0..3; h=1 -> u pair + 0
            f16x8 zf;
            if (h == 0) {
                zf = u4_to_h8(zplA[rowb + n]);
            } else {
                const uint2 b = zplB[rowb + n];
                zf = u4_to_h8(make_uint4(b.x, b.y, 0u, 0u));
            }

            const f32x16 z16 = {0.f,0.f,0.f,0.f,0.f,0.f,0.f,0.f,
                                0.f,0.f,0.f,0.f,0.f,0.f,0.f,0.f};

            // ---- build t[16]: SEQUENTIAL c1 halves sharing one 16-AGPR
            // accumulator (pins keep c1b from hoisting over t[0..7]).
            unsigned int t[16];
            {
                f32x16 c1 = __builtin_amdgcn_mfma_f32_32x32x16_f16(u4_to_h8(sA0[0][lz]), zf, z16, 0, 0, 0);
                #pragma unroll
                for (int a = 0; a < 4; ++a) {
                    t[2 * a + 0] = h2_bits(tanh_pk(pack2(c1[4 * a],     c1[4 * a + 1])));
                    t[2 * a + 1] = h2_bits(tanh_pk(pack2(c1[4 * a + 2], c1[4 * a + 3])));
                }
            }
            __builtin_amdgcn_sched_barrier(0);
            {
                f32x16 c1 = __builtin_amdgcn_mfma_f32_32x32x16_f16(u4_to_h8(sA0[1][lz]), zf, z16, 0, 0, 0);
                #pragma unroll
                for (int a = 0; a < 4; ++a) {
                    t[8 + 2 * a + 0] = h2_bits(tanh_pk(pack2(c1[4 * a],     c1[4 * a + 1])));
                    t[8 + 2 * a + 1] = h2_bits(tanh_pk(pack2(c1[4 * a + 2], c1[4 * a + 3])));
                }
            }
            __builtin_amdgcn_sched_barrier(0);

            const unsigned int* w2z = &w2l[zero];
            float accA, accB;

            // ---- chain A (Mh=0) + fused layer 3: one 16-AGPR c2 ----
            {
                f32x16 c2 = z16;
                #pragma unroll
                for (int kc = 0; kc < 4; ++kc) {
                    const int q = 8 * (kc >> 1) + 4 * (kc & 1);
                    u32x2 r0 = __builtin_amdgcn_permlane32_swap(t[q + 0], t[q + 2], false, false);
                    u32x2 r1 = __builtin_amdgcn_permlane32_swap(t[q + 1], t[q + 3], false, false);
                    const f16x8 hb = u4_to_h8(make_uint4(r0.x, r1.x, r0.y, r1.y));
                    c2 = __builtin_amdgcn_mfma_f32_32x32x16_f16(u4_to_h8(sA1[kc][lz]), hb, c2, 0, 0, 0);
                }
                float p0 = 0.f, p1 = 0.f;
                #pragma unroll
                for (int a = 0; a < 4; ++a) {
                    const int r = 4 * a;
                    const uint2 wa = *(const uint2*)&w2z[4 * a + 2 * h];
                    if (a & 1) {
                        p1 = __builtin_amdgcn_fdot2(tanh_pk(pack2(c2[r], c2[r + 1])), bits_h2(wa.x), p1, false);
                        p1 = __builtin_amdgcn_fdot2(tanh_pk(pack2(c2[r + 2], c2[r + 3])), bits_h2(wa.y), p1, false);
                    } else {
                        p0 = __builtin_amdgcn_fdot2(tanh_pk(pack2(c2[r], c2[r + 1])), bits_h2(wa.x), p0, false);
                        p0 = __builtin_amdgcn_fdot2(tanh_pk(pack2(c2[r + 2], c2[r + 3])), bits_h2(wa.y), p0, false);
                    }
                }
                accA = p0 + p1;
            }
            __builtin_amdgcn_sched_barrier(0);
            // ---- chain B (Mh=1) + fused layer 3: reuses the same regs ----
            {
                f32x16 c2 = z16;
                #pragma unroll
                for (int kc = 0; kc < 4; ++kc) {
                    const int q = 8 * (kc >> 1) + 4 * (kc & 1);
                    u32x2 r0 = __builtin_amdgcn_permlane32_swap(t[q + 0], t[q + 2], false, false);
                    u32x2 r1 = __builtin_amdgcn_permlane32_swap(t[q + 1], t[q + 3], false, false);
                    const f16x8 hb = u4_to_h8(make_uint4(r0.x, r1.x, r0.y, r1.y));
                    c2 = __builtin_amdgcn_mfma_f32_32x32x16_f16(u4_to_h8(sA1[4 + kc][lz]), hb, c2, 0, 0, 0);
                }
                float q0 = 0.f, q1 = 0.f;
                #pragma unroll
                for (int a = 0; a < 4; ++a) {
                    const int r = 4 * a;
                    const uint2 wb = *(const uint2*)&w2z[16 + 4 * a + 2 * h];
                    if (a & 1) {
                        q1 = __builtin_amdgcn_fdot2(tanh_pk(pack2(c2[r], c2[r + 1])), bits_h2(wb.x), q1, false);
                        q1 = __builtin_amdgcn_fdot2(tanh_pk(pack2(c2[r + 2], c2[r + 3])), bits_h2(wb.y), q1, false);
                    } else {
                        q0 = __builtin_amdgcn_fdot2(tanh_pk(pack2(c2[r], c2[r + 1])), bits_h2(wb.x), q0, false);
                        q0 = __builtin_amdgcn_fdot2(tanh_pk(pack2(c2[r + 2], c2[r + 3])), bits_h2(wb.y), q0, false);
                    }
                }
                accB = q0 + q1;
            }

            float acc = accA + accB;
            acc += __shfl_xor(acc, 32);       // combine h=0/h=1 halves

            if (lid < 32)
                out[(rbase + rowb + n) * N_STATES + s] = acc;
        }
    }
}

extern "C" void kernel_launch(void* const* d_in, const int* in_sizes, int n_in,
                              void* d_out, int out_size, void* d_ws, size_t ws_size,
                              hipStream_t stream) {
    const float* x_f = (const float*)d_in[0];
    const float* x_b = (const float*)d_in[1];
    const float* u   = (const float*)d_in[2];
    const float* W0  = (const float*)d_in[3];
    const float* W1  = (const float*)d_in[4];
    const float* W2  = (const float*)d_in[5];
    float* out = (float*)d_out;

    const int nb = in_sizes[0] / 8;                 // 131072 = 128 * 1024
    dim3 grid(nb / (256 * CHUNK), N_STATES);        // (128, 16) = 2048 blocks
    fans_mfma_kernel<<<grid, 256, 0, stream>>>(x_f, x_b, u, W0, W1, W2, out);
}